// Round 9
// baseline (1257.004 us; speedup 1.0000x reference)
//
#include <hip/hip_runtime.h>
#include <math.h>

// ---- NSA hyperparameters (compile-time, matches reference config) ----
constexpr int kT    = 2048;
constexpr int kHQ   = 16;
constexpr int kD    = 128;
constexpr int kKS   = 32;
constexpr int kST   = 16;
constexpr int kBS   = 64;
constexpr int kM    = (kT - kKS) / kST + 1;   // 127 compressed tokens
constexpr int kNB   = (kT + kBS - 1) / kBS;   // 32 selection blocks
constexpr int kTopN = 16;
constexpr int kNInit = 2;
constexpr int kWIN  = 512;
constexpr float kNEG = -1e30f;
constexpr float kScale = 0.08838834764831845f; // 128^-0.5

constexpr int kPad    = 32;
constexpr int kKBRows = kT + kPad; // 2080
constexpr int kVTCols = kT + kPad; // 2080

// K2 (cmp-attn) LDS strides
constexpr int kQS2 = kD + 4;   // 132 floats
constexpr int kPS2 = 132;      // fp32 probs
constexpr int kPB2 = 136;      // bf16 probs

// K4 single-wave attention: P row stride (fp16 halfwords)
constexpr int kPSt = 72;

typedef __attribute__((ext_vector_type(8))) short short8;
typedef __attribute__((ext_vector_type(8))) _Float16 half8;
typedef __attribute__((ext_vector_type(4))) float floatx4;

// RNE float -> bf16 bits
__device__ inline short f2bf(float x) {
    unsigned u = __float_as_uint(x);
    unsigned r = (u + 0x7fffu + ((u >> 16) & 1u)) >> 16;
    return (short)r;
}

// ---------------------------------------------------------------------
// K1: fused staging.  blocks [0,2080): bf16 K rows + fp16 V^T cols.
// blocks [2080,2208): mean-pool cmp_k fp32 + cmp V^T bf16.  block=(128)
// ---------------------------------------------------------------------
__global__ void k_stage(const float* __restrict__ k, const float* __restrict__ v,
                        short* __restrict__ kb, _Float16* __restrict__ vt,
                        float* __restrict__ cmp_k, short* __restrict__ cvt) {
    const int bid = blockIdx.x;
    const int d = threadIdx.x;
    if (bid < kKBRows) {
        const int row = bid;
        if (row < kT) {
            kb[row * kD + d] = f2bf(k[(size_t)row * kD + d]);
            vt[(size_t)d * kVTCols + row] = (_Float16)v[(size_t)row * kD + d];
        } else {
            kb[row * kD + d] = 0;
            vt[(size_t)d * kVTCols + row] = (_Float16)0.f;
        }
    } else {
        const int m = bid - kKBRows;        // 0..127 (127 = zero pad row)
        float sk = 0.f, sv = 0.f;
        if (m < kM) {
            const int base = m * kST;
            #pragma unroll
            for (int i = 0; i < kKS; ++i) {
                sk += k[(size_t)(base + i) * kD + d];
                sv += v[(size_t)(base + i) * kD + d];
            }
            sk *= (1.0f / kKS);
            sv *= (1.0f / kKS);
        }
        cmp_k[m * kD + d] = sk;
        cvt[d * 128 + m] = f2bf(sv);
    }
}

// ---------------------------------------------------------------------
// K2: compressed attention, all 16 heads of one t.
// QK + softmax + slc_p: fp32, unchanged (selection-sensitive).
// PV: bf16 MFMA.  grid=(T), block=(256)
// ---------------------------------------------------------------------
__global__ __launch_bounds__(256) void k_cmp_attn(
        const float* __restrict__ q, const float* __restrict__ cw,
        const float* __restrict__ cmp_k, const short* __restrict__ cvt,
        float* __restrict__ slc_p, float* __restrict__ out) {
    const int t = blockIdx.x;
    const int tid = threadIdx.x;
    const int wave = tid >> 6;
    const int lane = tid & 63;
    const int l15 = lane & 15;
    const int quad = lane >> 4;

    __shared__ float q_s[kHQ * kQS2];
    __shared__ float p_s[kHQ * kPS2];
    __shared__ short Pb[kHQ * kPB2];

    for (int i = tid; i < kHQ * kD; i += 256) {
        int h = i >> 7, d = i & 127;
        q_s[h * kQS2 + d] = q[(size_t)t * kHQ * kD + i];
    }
    __syncthreads();

    const int nvalid = (t >= kKS - 1) ? min(kM, (t - (kKS - 1)) / kST + 1) : 0;

    for (int idx = tid; idx < nvalid * 4; idx += 256) {
        const int m = idx >> 2;
        const int h0 = (idx & 3) * 4;
        const float4* k4 = (const float4*)(cmp_k + (size_t)m * kD);
        float a0 = 0.f, a1 = 0.f, a2 = 0.f, a3 = 0.f;
        #pragma unroll
        for (int i = 0; i < kD / 4; ++i) {
            const float4 b = k4[i];
            const float4 qa = *(const float4*)&q_s[(h0 + 0) * kQS2 + i * 4];
            const float4 qb = *(const float4*)&q_s[(h0 + 1) * kQS2 + i * 4];
            const float4 qc = *(const float4*)&q_s[(h0 + 2) * kQS2 + i * 4];
            const float4 qd = *(const float4*)&q_s[(h0 + 3) * kQS2 + i * 4];
            a0 = fmaf(qa.x, b.x, fmaf(qa.y, b.y, fmaf(qa.z, b.z, fmaf(qa.w, b.w, a0))));
            a1 = fmaf(qb.x, b.x, fmaf(qb.y, b.y, fmaf(qb.z, b.z, fmaf(qb.w, b.w, a1))));
            a2 = fmaf(qc.x, b.x, fmaf(qc.y, b.y, fmaf(qc.z, b.z, fmaf(qc.w, b.w, a2))));
            a3 = fmaf(qd.x, b.x, fmaf(qd.y, b.y, fmaf(qd.z, b.z, fmaf(qd.w, b.w, a3))));
        }
        p_s[(h0 + 0) * kPS2 + m] = a0 * kScale;
        p_s[(h0 + 1) * kPS2 + m] = a1 * kScale;
        p_s[(h0 + 2) * kPS2 + m] = a2 * kScale;
        p_s[(h0 + 3) * kPS2 + m] = a3 * kScale;
    }
    __syncthreads();

    if (tid < kHQ) {
        float* p = p_s + tid * kPS2;
        short* pb = Pb + tid * kPB2;
        if (nvalid == 0) {
            for (int m = 0; m < 128; ++m) { p[m] = 0.f; pb[m] = 0; }
        } else {
            float mx = kNEG;
            for (int m = 0; m < nvalid; ++m) mx = fmaxf(mx, p[m]);
            float l = 0.f;
            for (int m = 0; m < nvalid; ++m) { float e = __expf(p[m] - mx); p[m] = e; l += e; }
            float inv = 1.f / l;
            for (int m = 0; m < nvalid; ++m) { float pn = p[m] * inv; p[m] = pn; pb[m] = f2bf(pn); }
            for (int m = nvalid; m < 128; ++m) { p[m] = 0.f; pb[m] = 0; }
        }
    }
    __syncthreads();

    if (tid < kNB) {
        const int b = tid;
        const int m0 = 4 * b;
        float acc = 0.f;
        for (int h = 0; h < kHQ; ++h) {
            const float* p = p_s + h * kPS2;
            float a = 0.f;
            a += p[m0];
            a += p[m0 + 1];
            a += p[m0 + 2];
            a += 0.5f * p[m0 + 3];
            if (m0 - 1 >= 0) a += 0.5f * p[m0 - 1];
            acc += a;
        }
        slc_p[t * kNB + b] = acc;
    }

    const int dimbase = wave * 32;
    floatx4 o[2] = {{0,0,0,0},{0,0,0,0}};
    #pragma unroll
    for (int kc = 0; kc < 4; ++kc) {
        const short8 ap = *(const short8*)&Pb[l15 * kPB2 + kc * 32 + quad * 8];
        #pragma unroll
        for (int nt = 0; nt < 2; ++nt) {
            const short8 b = *(const short8*)(cvt + (size_t)(dimbase + nt * 16 + l15) * 128 + kc * 32 + quad * 8);
            o[nt] = __builtin_amdgcn_mfma_f32_16x16x32_bf16(ap, b, o[nt], 0, 0, 0);
        }
    }

    #pragma unroll
    for (int r = 0; r < 4; ++r) {
        const int head = quad * 4 + r;
        const float c0 = cw[((size_t)t * kHQ + head) * 3 + 0];
        const float w0 = 1.f / (1.f + __expf(-c0));
        #pragma unroll
        for (int nt = 0; nt < 2; ++nt)
            out[((size_t)t * kHQ + head) * kD + dimbase + nt * 16 + l15] = w0 * o[nt][r];
    }
}

// ---------------------------------------------------------------------
// K3: top-k -> 32-bit block membership mask per t (always 16 bits set).
// ---------------------------------------------------------------------
__global__ void k_topk(const float* __restrict__ slc_p, unsigned* __restrict__ sel_mask) {
    const int t = blockIdx.x * blockDim.x + threadIdx.x;
    if (t >= kT) return;
    const int cur = t / kBS;
    float vals[kNB];
    #pragma unroll
    for (int b = 0; b < kNB; ++b) {
        float x = slc_p[t * kNB + b];
        if (b > cur) x = kNEG;
        if (b < kNInit || b == cur) x = 1e30f;
        vals[b] = x;
    }
    unsigned mask = 0;
    for (int n = 0; n < kTopN; ++n) {
        float best = -3.0e38f; int bi = 0;
        #pragma unroll
        for (int b = 0; b < kNB; ++b) {
            bool taken = (mask >> b) & 1u;
            if (!taken && vals[b] > best) { best = vals[b]; bi = b; }
        }
        mask |= (1u << bi);
    }
    sel_mask[t] = mask;
}

// ---------------------------------------------------------------------
// K4: single-wave select+SWA attention.  One wave = one query t, all 16
// heads.  ZERO barriers: QK acc, softmax state, alpha all in registers;
// the only cross-lane step is the P C-layout->A-layout transpose through
// a wave-private LDS buffer (DS pipe is in-order per wave -> no barrier).
// Loop over union of selected | window blocks; sel and SWA share QK.
// grid=(T), block=(64).
// ---------------------------------------------------------------------
__global__ __launch_bounds__(64, 2) void k_attn_wave(
        const float* __restrict__ q, const short* __restrict__ kb,
        const _Float16* __restrict__ vt, const float* __restrict__ cw,
        const unsigned* __restrict__ sel_mask, float* __restrict__ out) {
    const int t = blockIdx.x;
    const int lane = threadIdx.x;
    const int l15 = lane & 15;
    const int quad = lane >> 4;

    __shared__ _Float16 Psel[16 * kPSt];   // 2.25 KB
    __shared__ _Float16 Pswa[16 * kPSt];   // 2.25 KB

    // A-fragments: q[t][head=l15][.] -> bf16, k-chunk c
    short8 aq[4];
    {
        const float* qp = q + ((size_t)t * kHQ + l15) * kD + quad * 8;
        #pragma unroll
        for (int c = 0; c < 4; ++c) {
            const float4 f0 = *(const float4*)(qp + c * 32);
            const float4 f1 = *(const float4*)(qp + c * 32 + 4);
            short8 a;
            a[0] = f2bf(f0.x); a[1] = f2bf(f0.y); a[2] = f2bf(f0.z); a[3] = f2bf(f0.w);
            a[4] = f2bf(f1.x); a[5] = f2bf(f1.y); a[6] = f2bf(f1.z); a[7] = f2bf(f1.w);
            aq[c] = a;
        }
    }

    const unsigned selm = sel_mask[t];
    const int cur = t >> 6;
    const int s0 = max(0, t - kWIN + 1);

    // per-row online softmax state; lane handles rows (heads) quad*4+r
    float msel[4], lsel[4], mswa[4], lswa[4];
    #pragma unroll
    for (int r = 0; r < 4; ++r) { msel[r] = kNEG; lsel[r] = 0.f; mswa[r] = kNEG; lswa[r] = 0.f; }

    // PV accumulators: wave owns all 128 dims (8 n-tiles)
    floatx4 osel[8], oswa[8];
    #pragma unroll
    for (int nt = 0; nt < 8; ++nt) { osel[nt] = (floatx4){0,0,0,0}; oswa[nt] = (floatx4){0,0,0,0}; }

    for (int b = 0; b <= cur; ++b) {
        const bool bsel = (selm >> b) & 1u;
        const bool bswa = (b * kBS + kBS - 1) >= s0;
        if (!bsel && !bswa) continue;

        // ---- QK: 16 heads x 64 keys, K direct from global (coalesced) ----
        floatx4 acc[4];
        #pragma unroll
        for (int kt = 0; kt < 4; ++kt) {
            acc[kt] = (floatx4){0,0,0,0};
            const short* kp = kb + (size_t)(b * kBS + kt * 16 + l15) * kD + quad * 8;
            #pragma unroll
            for (int c = 0; c < 4; ++c)
                acc[kt] = __builtin_amdgcn_mfma_f32_16x16x32_bf16(aq[c], *(const short8*)(kp + c * 32), acc[kt], 0, 0, 0);
        }

        bool ca[4], wi[4];
        #pragma unroll
        for (int kt = 0; kt < 4; ++kt) {
            const int key = b * kBS + kt * 16 + l15;
            ca[kt] = key <= t;
            wi[kt] = ca[kt] && (t - key) < kWIN;
        }

        // ---- online softmax (sel + swa share scores); alpha in regs ----
        float as_[4], aw_[4];
        #pragma unroll
        for (int r = 0; r < 4; ++r) {
            float mxs = kNEG, mxw = kNEG;
            #pragma unroll
            for (int kt = 0; kt < 4; ++kt) {
                const float s = acc[kt][r] * kScale;
                if (bsel && ca[kt]) mxs = fmaxf(mxs, s);
                if (wi[kt]) mxw = fmaxf(mxw, s);
            }
            #pragma unroll
            for (int off = 8; off; off >>= 1) {
                mxs = fmaxf(mxs, __shfl_xor(mxs, off, 16));
                mxw = fmaxf(mxw, __shfl_xor(mxw, off, 16));
            }
            const float msn = fmaxf(msel[r], mxs);
            const float mwn = fmaxf(mswa[r], mxw);
            as_[r] = __expf(msel[r] - msn);
            aw_[r] = __expf(mswa[r] - mwn);
            float sums = 0.f, sumw = 0.f;
            const int prow = (quad * 4 + r) * kPSt + l15;
            #pragma unroll
            for (int kt = 0; kt < 4; ++kt) {
                const float s = acc[kt][r] * kScale;
                const float es = (bsel && ca[kt]) ? __expf(s - msn) : 0.f;
                const float ew = wi[kt] ? __expf(s - mwn) : 0.f;
                sums += es; sumw += ew;
                if (bsel) Psel[prow + kt * 16] = (_Float16)es;
                if (bswa) Pswa[prow + kt * 16] = (_Float16)ew;
            }
            #pragma unroll
            for (int off = 8; off; off >>= 1) {
                sums += __shfl_xor(sums, off, 16);
                sumw += __shfl_xor(sumw, off, 16);
            }
            lsel[r] = lsel[r] * as_[r] + sums; msel[r] = msn;
            lswa[r] = lswa[r] * aw_[r] + sumw; mswa[r] = mwn;
        }

        // ---- PV: rescale (alpha per row r, same lane), then MFMA ----
        if (bsel) {
            #pragma unroll
            for (int nt = 0; nt < 8; ++nt)
                #pragma unroll
                for (int r = 0; r < 4; ++r) osel[nt][r] *= as_[r];
        }
        if (bswa) {
            #pragma unroll
            for (int nt = 0; nt < 8; ++nt)
                #pragma unroll
                for (int r = 0; r < 4; ++r) oswa[nt][r] *= aw_[r];
        }
        #pragma unroll
        for (int kc = 0; kc < 2; ++kc) {
            const half8 aps = *(const half8*)&Psel[l15 * kPSt + kc * 32 + quad * 8];
            const half8 apw = *(const half8*)&Pswa[l15 * kPSt + kc * 32 + quad * 8];
            #pragma unroll
            for (int nt = 0; nt < 8; ++nt) {
                const half8 vf = *(const half8*)(vt + (size_t)(nt * 16 + l15) * kVTCols
                                                 + b * kBS + kc * 32 + quad * 8);
                if (bsel) osel[nt] = __builtin_amdgcn_mfma_f32_16x16x32_f16(aps, vf, osel[nt], 0, 0, 0);
                if (bswa) oswa[nt] = __builtin_amdgcn_mfma_f32_16x16x32_f16(apw, vf, oswa[nt], 0, 0, 0);
            }
        }
    }

    // ---- epilogue: normalize + sigmoid combine ----
    #pragma unroll
    for (int r = 0; r < 4; ++r) {
        const int h = quad * 4 + r;
        const float ls = 1.f / lsel[r];
        const float lw = 1.f / lswa[r];
        const float c1 = cw[((size_t)t * kHQ + h) * 3 + 1];
        const float c2 = cw[((size_t)t * kHQ + h) * 3 + 2];
        const float w1 = 1.f / (1.f + __expf(-c1));
        const float w2 = 1.f / (1.f + __expf(-c2));
        #pragma unroll
        for (int nt = 0; nt < 8; ++nt) {
            const int dim = nt * 16 + l15;
            float* op = out + ((size_t)t * kHQ + h) * kD + dim;
            *op += w1 * osel[nt][r] * ls + w2 * oswa[nt][r] * lw;
        }
    }
}

// ---------------------------------------------------------------------
extern "C" void kernel_launch(void* const* d_in, const int* in_sizes, int n_in,
                              void* d_out, int out_size, void* d_ws, size_t ws_size,
                              hipStream_t stream) {
    const float* q  = (const float*)d_in[0];
    const float* k  = (const float*)d_in[1];
    const float* v  = (const float*)d_in[2];
    const float* cw = (const float*)d_in[3];
    float* out = (float*)d_out;

    float* ws = (float*)d_ws;
    float* cmp_k = ws;                                   // 128*128 fp32
    float* slc_p = cmp_k + 128 * kD;                     // T*NB fp32
    unsigned* sel_mask = (unsigned*)(slc_p + kT * kNB);  // T u32
    short* kb      = (short*)(sel_mask + kT);            // kKBRows*kD bf16
    _Float16* vt   = (_Float16*)(kb + (size_t)kKBRows * kD);  // kD*kVTCols fp16
    short* cvt     = (short*)(vt + (size_t)kD * kVTCols);     // 128*128 bf16

    k_stage<<<dim3(kKBRows + 128), dim3(kD), 0, stream>>>(k, v, kb, vt, cmp_k, cvt);
    k_cmp_attn<<<dim3(kT), dim3(256), 0, stream>>>(q, cw, cmp_k, cvt, slc_p, out);
    k_topk<<<dim3(kT / 256), dim3(256), 0, stream>>>(slc_p, sel_mask);
    k_attn_wave<<<dim3(kT), dim3(64), 0, stream>>>(q, kb, vt, cw, sel_mask, out);
}

// Round 10
// 273.241 us; speedup vs baseline: 4.6004x; 4.6004x over previous
//
#include <hip/hip_runtime.h>
#include <math.h>

// ---- NSA hyperparameters (compile-time, matches reference config) ----
constexpr int kT    = 2048;
constexpr int kHQ   = 16;
constexpr int kD    = 128;
constexpr int kKS   = 32;
constexpr int kST   = 16;
constexpr int kBS   = 64;
constexpr int kM    = (kT - kKS) / kST + 1;   // 127 compressed tokens
constexpr int kNB   = (kT + kBS - 1) / kBS;   // 32 selection blocks
constexpr int kTopN = 16;
constexpr int kNInit = 2;
constexpr int kWIN  = 512;
constexpr float kNEG = -1e30f;
constexpr float kScale = 0.08838834764831845f; // 128^-0.5

constexpr int kPad    = 32;
constexpr int kKBRows = kT + kPad; // 2080
constexpr int kVTCols = kT + kPad; // 2080

// K2 (cmp-attn) LDS strides
constexpr int kQS2 = kD + 4;   // 132 floats
constexpr int kPS2 = 132;      // fp32 probs
constexpr int kPB2 = 136;      // bf16 probs

// K4 tiled attention (kQT=2: 2 waves, 2 queries, grid=1024)
constexpr int kQT   = 2;          // queries per tile
constexpr int kKstS = 136;        // staged K row stride (bf16 halfwords)
constexpr int kPSt  = 72;         // P row stride (fp16)

typedef __attribute__((ext_vector_type(8))) short short8;
typedef __attribute__((ext_vector_type(8))) _Float16 half8;
typedef __attribute__((ext_vector_type(4))) float floatx4;

// RNE float -> bf16 bits
__device__ inline short f2bf(float x) {
    unsigned u = __float_as_uint(x);
    unsigned r = (u + 0x7fffu + ((u >> 16) & 1u)) >> 16;
    return (short)r;
}

// ---------------------------------------------------------------------
// K1: fused staging.  blocks [0,2080): bf16 K rows + fp16 V^T cols.
// blocks [2080,2208): mean-pool cmp_k fp32 + cmp V^T bf16.  block=(128)
// ---------------------------------------------------------------------
__global__ void k_stage(const float* __restrict__ k, const float* __restrict__ v,
                        short* __restrict__ kb, _Float16* __restrict__ vt,
                        float* __restrict__ cmp_k, short* __restrict__ cvt) {
    const int bid = blockIdx.x;
    const int d = threadIdx.x;
    if (bid < kKBRows) {
        const int row = bid;
        if (row < kT) {
            kb[row * kD + d] = f2bf(k[(size_t)row * kD + d]);
            vt[(size_t)d * kVTCols + row] = (_Float16)v[(size_t)row * kD + d];
        } else {
            kb[row * kD + d] = 0;
            vt[(size_t)d * kVTCols + row] = (_Float16)0.f;
        }
    } else {
        const int m = bid - kKBRows;        // 0..127 (127 = zero pad row)
        float sk = 0.f, sv = 0.f;
        if (m < kM) {
            const int base = m * kST;
            #pragma unroll
            for (int i = 0; i < kKS; ++i) {
                sk += k[(size_t)(base + i) * kD + d];
                sv += v[(size_t)(base + i) * kD + d];
            }
            sk *= (1.0f / kKS);
            sv *= (1.0f / kKS);
        }
        cmp_k[m * kD + d] = sk;
        cvt[d * 128 + m] = f2bf(sv);
    }
}

// ---------------------------------------------------------------------
// K2: compressed attention, all 16 heads of one t.
// QK + softmax + slc_p: fp32, unchanged (selection-sensitive).
// PV: bf16 MFMA.  grid=(T), block=(256)
// ---------------------------------------------------------------------
__global__ __launch_bounds__(256) void k_cmp_attn(
        const float* __restrict__ q, const float* __restrict__ cw,
        const float* __restrict__ cmp_k, const short* __restrict__ cvt,
        float* __restrict__ slc_p, float* __restrict__ out) {
    const int t = blockIdx.x;
    const int tid = threadIdx.x;
    const int wave = tid >> 6;
    const int lane = tid & 63;
    const int l15 = lane & 15;
    const int quad = lane >> 4;

    __shared__ float q_s[kHQ * kQS2];
    __shared__ float p_s[kHQ * kPS2];
    __shared__ short Pb[kHQ * kPB2];

    for (int i = tid; i < kHQ * kD; i += 256) {
        int h = i >> 7, d = i & 127;
        q_s[h * kQS2 + d] = q[(size_t)t * kHQ * kD + i];
    }
    __syncthreads();

    const int nvalid = (t >= kKS - 1) ? min(kM, (t - (kKS - 1)) / kST + 1) : 0;

    for (int idx = tid; idx < nvalid * 4; idx += 256) {
        const int m = idx >> 2;
        const int h0 = (idx & 3) * 4;
        const float4* k4 = (const float4*)(cmp_k + (size_t)m * kD);
        float a0 = 0.f, a1 = 0.f, a2 = 0.f, a3 = 0.f;
        #pragma unroll
        for (int i = 0; i < kD / 4; ++i) {
            const float4 b = k4[i];
            const float4 qa = *(const float4*)&q_s[(h0 + 0) * kQS2 + i * 4];
            const float4 qb = *(const float4*)&q_s[(h0 + 1) * kQS2 + i * 4];
            const float4 qc = *(const float4*)&q_s[(h0 + 2) * kQS2 + i * 4];
            const float4 qd = *(const float4*)&q_s[(h0 + 3) * kQS2 + i * 4];
            a0 = fmaf(qa.x, b.x, fmaf(qa.y, b.y, fmaf(qa.z, b.z, fmaf(qa.w, b.w, a0))));
            a1 = fmaf(qb.x, b.x, fmaf(qb.y, b.y, fmaf(qb.z, b.z, fmaf(qb.w, b.w, a1))));
            a2 = fmaf(qc.x, b.x, fmaf(qc.y, b.y, fmaf(qc.z, b.z, fmaf(qc.w, b.w, a2))));
            a3 = fmaf(qd.x, b.x, fmaf(qd.y, b.y, fmaf(qd.z, b.z, fmaf(qd.w, b.w, a3))));
        }
        p_s[(h0 + 0) * kPS2 + m] = a0 * kScale;
        p_s[(h0 + 1) * kPS2 + m] = a1 * kScale;
        p_s[(h0 + 2) * kPS2 + m] = a2 * kScale;
        p_s[(h0 + 3) * kPS2 + m] = a3 * kScale;
    }
    __syncthreads();

    if (tid < kHQ) {
        float* p = p_s + tid * kPS2;
        short* pb = Pb + tid * kPB2;
        if (nvalid == 0) {
            for (int m = 0; m < 128; ++m) { p[m] = 0.f; pb[m] = 0; }
        } else {
            float mx = kNEG;
            for (int m = 0; m < nvalid; ++m) mx = fmaxf(mx, p[m]);
            float l = 0.f;
            for (int m = 0; m < nvalid; ++m) { float e = __expf(p[m] - mx); p[m] = e; l += e; }
            float inv = 1.f / l;
            for (int m = 0; m < nvalid; ++m) { float pn = p[m] * inv; p[m] = pn; pb[m] = f2bf(pn); }
            for (int m = nvalid; m < 128; ++m) { p[m] = 0.f; pb[m] = 0; }
        }
    }
    __syncthreads();

    if (tid < kNB) {
        const int b = tid;
        const int m0 = 4 * b;
        float acc = 0.f;
        for (int h = 0; h < kHQ; ++h) {
            const float* p = p_s + h * kPS2;
            float a = 0.f;
            a += p[m0];
            a += p[m0 + 1];
            a += p[m0 + 2];
            a += 0.5f * p[m0 + 3];
            if (m0 - 1 >= 0) a += 0.5f * p[m0 - 1];
            acc += a;
        }
        slc_p[t * kNB + b] = acc;
    }

    const int dimbase = wave * 32;
    floatx4 o[2] = {{0,0,0,0},{0,0,0,0}};
    #pragma unroll
    for (int kc = 0; kc < 4; ++kc) {
        const short8 ap = *(const short8*)&Pb[l15 * kPB2 + kc * 32 + quad * 8];
        #pragma unroll
        for (int nt = 0; nt < 2; ++nt) {
            const short8 b = *(const short8*)(cvt + (size_t)(dimbase + nt * 16 + l15) * 128 + kc * 32 + quad * 8);
            o[nt] = __builtin_amdgcn_mfma_f32_16x16x32_bf16(ap, b, o[nt], 0, 0, 0);
        }
    }

    #pragma unroll
    for (int r = 0; r < 4; ++r) {
        const int head = quad * 4 + r;
        const float c0 = cw[((size_t)t * kHQ + head) * 3 + 0];
        const float w0 = 1.f / (1.f + __expf(-c0));
        #pragma unroll
        for (int nt = 0; nt < 2; ++nt)
            out[((size_t)t * kHQ + head) * kD + dimbase + nt * 16 + l15] = w0 * o[nt][r];
    }
}

// ---------------------------------------------------------------------
// K3: top-k -> 32-bit block membership mask per t (always 16 bits set).
// ---------------------------------------------------------------------
__global__ void k_topk(const float* __restrict__ slc_p, unsigned* __restrict__ sel_mask) {
    const int t = blockIdx.x * blockDim.x + threadIdx.x;
    if (t >= kT) return;
    const int cur = t / kBS;
    float vals[kNB];
    #pragma unroll
    for (int b = 0; b < kNB; ++b) {
        float x = slc_p[t * kNB + b];
        if (b > cur) x = kNEG;
        if (b < kNInit || b == cur) x = 1e30f;
        vals[b] = x;
    }
    unsigned mask = 0;
    for (int n = 0; n < kTopN; ++n) {
        float best = -3.0e38f; int bi = 0;
        #pragma unroll
        for (int b = 0; b < kNB; ++b) {
            bool taken = (mask >> b) & 1u;
            if (!taken && vals[b] > best) { best = vals[b]; bi = b; }
        }
        mask |= (1u << bi);
    }
    sel_mask[t] = mask;
}

// ---------------------------------------------------------------------
// K4: query-tiled select+SWA attention (R8 structure, kQT=2).
// One workgroup = 2 consecutive t's x 16 heads, 2 waves.  grid=(T/2).
// Loop over union of selected | window blocks: stage K (64 keys) in LDS,
// one QK per wave (its own t), two masked online softmaxes sharing the
// scores, two PV accumulations (wave owns 64 dims).  Cross-wave staging
// keeps K/V L2-resident (R9 lesson: wave-private gathers thrash L2).
// ---------------------------------------------------------------------
__global__ __launch_bounds__(128, 2) void k_attn_tile(
        const float* __restrict__ q, const short* __restrict__ kb,
        const _Float16* __restrict__ vt, const float* __restrict__ cw,
        const unsigned* __restrict__ sel_mask, float* __restrict__ out) {
    const int t0 = blockIdx.x * kQT;
    const int tid = threadIdx.x;
    const int wave = tid >> 6;
    const int lane = tid & 63;
    const int l15 = lane & 15;
    const int quad = lane >> 4;

    __shared__ short Kst[64 * kKstS];            // 17.4 KB staged K block
    __shared__ _Float16 Psel[kQT * 16 * kPSt];   // 4.6 KB
    __shared__ _Float16 Pswa[kQT * 16 * kPSt];   // 4.6 KB
    __shared__ float alphaS[kQT * 16], alphaW[kQT * 16];
    __shared__ float linvS[kQT * 16], linvW[kQT * 16];
    __shared__ unsigned selm_s[kQT];

    const int t_w = t0 + wave;               // this wave's query (QK phase)

    // A-fragments: q[t_w][head=l15][.] -> bf16, k-chunk c
    short8 aq[4];
    {
        const float* qp = q + ((size_t)t_w * kHQ + l15) * kD + quad * 8;
        #pragma unroll
        for (int c = 0; c < 4; ++c) {
            const float4 f0 = *(const float4*)(qp + c * 32);
            const float4 f1 = *(const float4*)(qp + c * 32 + 4);
            short8 a;
            a[0] = f2bf(f0.x); a[1] = f2bf(f0.y); a[2] = f2bf(f0.z); a[3] = f2bf(f0.w);
            a[4] = f2bf(f1.x); a[5] = f2bf(f1.y); a[6] = f2bf(f1.z); a[7] = f2bf(f1.w);
            aq[c] = a;
        }
    }

    if (tid < kQT) selm_s[tid] = sel_mask[t0 + tid];
    __syncthreads();

    const unsigned selm_w = selm_s[wave];
    const unsigned u_union = selm_s[0] | selm_s[1];
    const int cur_max = (t0 + kQT - 1) >> 6;

    // per-row online softmax state (rows = quad*4+r heads of this wave's t)
    float msel[4], lsel[4], mswa[4], lswa[4];
    #pragma unroll
    for (int r = 0; r < 4; ++r) { msel[r] = kNEG; lsel[r] = 0.f; mswa[r] = kNEG; lswa[r] = 0.f; }

    // PV accumulators: wave owns dims [64w,64w+64); both Mtiles
    floatx4 osel[kQT][4], oswa[kQT][4];
    #pragma unroll
    for (int mt = 0; mt < kQT; ++mt)
        #pragma unroll
        for (int nt = 0; nt < 4; ++nt) {
            osel[mt][nt] = (floatx4){0,0,0,0};
            oswa[mt][nt] = (floatx4){0,0,0,0};
        }
    const int dimw = wave * 64;

    for (int b = 0; b <= cur_max; ++b) {
        const bool bsel = (u_union >> b) & 1u;
        const bool bswa = (b * kBS + kBS - 1) >= (t0 - (kWIN - 1));
        if (!bsel && !bswa) continue;

        // ---- stage K block: 64 rows x 128 dims bf16, coalesced ----
        {
            const int row = tid >> 1, seg = tid & 1;
            const short* src = kb + (size_t)(b * kBS + row) * kD + seg * 64;
            short* dst = Kst + row * kKstS + seg * 64;
            #pragma unroll
            for (int i = 0; i < 8; ++i)
                *(short8*)(dst + i * 8) = *(const short8*)(src + i * 8);
        }
        __syncthreads();   // Kst ready; prev PV done with P/alpha

        // ---- QK: wave computes its Mtile (16 heads x 64 keys) ----
        floatx4 acc[4];
        #pragma unroll
        for (int kt = 0; kt < 4; ++kt) {
            acc[kt] = (floatx4){0,0,0,0};
            #pragma unroll
            for (int c = 0; c < 4; ++c) {
                const short8 bf = *(const short8*)&Kst[(kt * 16 + l15) * kKstS + c * 32 + quad * 8];
                acc[kt] = __builtin_amdgcn_mfma_f32_16x16x32_bf16(aq[c], bf, acc[kt], 0, 0, 0);
            }
        }

        const bool mem = (selm_w >> b) & 1u;
        bool ca[4], wi[4];
        #pragma unroll
        for (int kt = 0; kt < 4; ++kt) {
            const int key = b * kBS + kt * 16 + l15;
            ca[kt] = key <= t_w;
            wi[kt] = ca[kt] && (t_w - key) < kWIN;
        }

        float axs[4], axw[4];
        #pragma unroll
        for (int r = 0; r < 4; ++r) {
            float mxs = kNEG, mxw = kNEG;
            #pragma unroll
            for (int kt = 0; kt < 4; ++kt) {
                const float s = acc[kt][r] * kScale;
                if (ca[kt] && mem) mxs = fmaxf(mxs, s);
                if (wi[kt]) mxw = fmaxf(mxw, s);
            }
            #pragma unroll
            for (int off = 8; off; off >>= 1) {
                mxs = fmaxf(mxs, __shfl_xor(mxs, off, 16));
                mxw = fmaxf(mxw, __shfl_xor(mxw, off, 16));
            }
            const float msn = fmaxf(msel[r], mxs);
            const float mwn = fmaxf(mswa[r], mxw);
            const float as_ = __expf(msel[r] - msn);
            const float aw_ = __expf(mswa[r] - mwn);
            float sums = 0.f, sumw = 0.f;
            const int prow = (wave * 16 + quad * 4 + r) * kPSt + l15;
            #pragma unroll
            for (int kt = 0; kt < 4; ++kt) {
                const float s = acc[kt][r] * kScale;
                const float es = (ca[kt] && mem) ? __expf(s - msn) : 0.f;
                const float ew = wi[kt] ? __expf(s - mwn) : 0.f;
                sums += es; sumw += ew;
                if (bsel) Psel[prow + kt * 16] = (_Float16)es;
                if (bswa) Pswa[prow + kt * 16] = (_Float16)ew;
            }
            #pragma unroll
            for (int off = 8; off; off >>= 1) {
                sums += __shfl_xor(sums, off, 16);
                sumw += __shfl_xor(sumw, off, 16);
            }
            lsel[r] = lsel[r] * as_ + sums; msel[r] = msn;
            lswa[r] = lswa[r] * aw_ + sumw; mswa[r] = mwn;
            axs[r] = as_; axw[r] = aw_;
        }
        if (l15 == 0) {
            *(float4*)&alphaS[wave * 16 + quad * 4] = make_float4(axs[0], axs[1], axs[2], axs[3]);
            *(float4*)&alphaW[wave * 16 + quad * 4] = make_float4(axw[0], axw[1], axw[2], axw[3]);
        }
        __syncthreads();   // P + alpha ready; all Kst reads done

        // ---- PV: wave owns dims [64w,64w+64); V frags shared by branches ----
        half8 vf[4][2];
        #pragma unroll
        for (int nt = 0; nt < 4; ++nt)
            #pragma unroll
            for (int kc = 0; kc < 2; ++kc)
                vf[nt][kc] = *(const half8*)(vt + (size_t)(dimw + nt * 16 + l15) * kVTCols
                                             + b * kBS + kc * 32 + quad * 8);
        if (bsel) {
            #pragma unroll
            for (int mt = 0; mt < kQT; ++mt) {
                const float4 a4 = *(const float4*)&alphaS[mt * 16 + quad * 4];
                const float av[4] = {a4.x, a4.y, a4.z, a4.w};
                #pragma unroll
                for (int nt = 0; nt < 4; ++nt)
                    #pragma unroll
                    for (int r = 0; r < 4; ++r) osel[mt][nt][r] *= av[r];
                #pragma unroll
                for (int kc = 0; kc < 2; ++kc) {
                    const half8 ap = *(const half8*)&Psel[(mt * 16 + l15) * kPSt + kc * 32 + quad * 8];
                    #pragma unroll
                    for (int nt = 0; nt < 4; ++nt)
                        osel[mt][nt] = __builtin_amdgcn_mfma_f32_16x16x32_f16(ap, vf[nt][kc], osel[mt][nt], 0, 0, 0);
                }
            }
        }
        if (bswa) {
            #pragma unroll
            for (int mt = 0; mt < kQT; ++mt) {
                const float4 a4 = *(const float4*)&alphaW[mt * 16 + quad * 4];
                const float av[4] = {a4.x, a4.y, a4.z, a4.w};
                #pragma unroll
                for (int nt = 0; nt < 4; ++nt)
                    #pragma unroll
                    for (int r = 0; r < 4; ++r) oswa[mt][nt][r] *= av[r];
                #pragma unroll
                for (int kc = 0; kc < 2; ++kc) {
                    const half8 ap = *(const half8*)&Pswa[(mt * 16 + l15) * kPSt + kc * 32 + quad * 8];
                    #pragma unroll
                    for (int nt = 0; nt < 4; ++nt)
                        oswa[mt][nt] = __builtin_amdgcn_mfma_f32_16x16x32_f16(ap, vf[nt][kc], oswa[mt][nt], 0, 0, 0);
                }
            }
        }
    }

    // ---- epilogue: normalizers + sigmoid combine ----
    if (l15 == 0) {
        *(float4*)&linvS[wave * 16 + quad * 4] =
            make_float4(1.f / lsel[0], 1.f / lsel[1], 1.f / lsel[2], 1.f / lsel[3]);
        *(float4*)&linvW[wave * 16 + quad * 4] =
            make_float4(1.f / lswa[0], 1.f / lswa[1], 1.f / lswa[2], 1.f / lswa[3]);
    }
    __syncthreads();

    #pragma unroll
    for (int mt = 0; mt < kQT; ++mt) {
        const int tt = t0 + mt;
        #pragma unroll
        for (int r = 0; r < 4; ++r) {
            const int h = quad * 4 + r;
            const float ls = linvS[mt * 16 + h];
            const float lw = linvW[mt * 16 + h];
            const float c1 = cw[((size_t)tt * kHQ + h) * 3 + 1];
            const float c2 = cw[((size_t)tt * kHQ + h) * 3 + 2];
            const float w1 = 1.f / (1.f + __expf(-c1));
            const float w2 = 1.f / (1.f + __expf(-c2));
            #pragma unroll
            for (int nt = 0; nt < 4; ++nt) {
                const int dim = dimw + nt * 16 + l15;
                float* op = out + ((size_t)tt * kHQ + h) * kD + dim;
                *op += w1 * osel[mt][nt][r] * ls + w2 * oswa[mt][nt][r] * lw;
            }
        }
    }
}

// ---------------------------------------------------------------------
extern "C" void kernel_launch(void* const* d_in, const int* in_sizes, int n_in,
                              void* d_out, int out_size, void* d_ws, size_t ws_size,
                              hipStream_t stream) {
    const float* q  = (const float*)d_in[0];
    const float* k  = (const float*)d_in[1];
    const float* v  = (const float*)d_in[2];
    const float* cw = (const float*)d_in[3];
    float* out = (float*)d_out;

    float* ws = (float*)d_ws;
    float* cmp_k = ws;                                   // 128*128 fp32
    float* slc_p = cmp_k + 128 * kD;                     // T*NB fp32
    unsigned* sel_mask = (unsigned*)(slc_p + kT * kNB);  // T u32
    short* kb      = (short*)(sel_mask + kT);            // kKBRows*kD bf16
    _Float16* vt   = (_Float16*)(kb + (size_t)kKBRows * kD);  // kD*kVTCols fp16
    short* cvt     = (short*)(vt + (size_t)kD * kVTCols);     // 128*128 bf16

    k_stage<<<dim3(kKBRows + 128), dim3(kD), 0, stream>>>(k, v, kb, vt, cmp_k, cvt);
    k_cmp_attn<<<dim3(kT), dim3(256), 0, stream>>>(q, cw, cmp_k, cvt, slc_p, out);
    k_topk<<<dim3(kT / 256), dim3(256), 0, stream>>>(slc_p, sel_mask);
    k_attn_tile<<<dim3(kT / kQT), dim3(128), 0, stream>>>(q, kb, vt, cw, sel_mask, out);
}

// Round 11
// 244.908 us; speedup vs baseline: 5.1326x; 1.1157x over previous
//
#include <hip/hip_runtime.h>
#include <math.h>

// ---- NSA hyperparameters (compile-time, matches reference config) ----
constexpr int kT    = 2048;
constexpr int kHQ   = 16;
constexpr int kD    = 128;
constexpr int kKS   = 32;
constexpr int kST   = 16;
constexpr int kBS   = 64;
constexpr int kM    = (kT - kKS) / kST + 1;   // 127 compressed tokens
constexpr int kNB   = (kT + kBS - 1) / kBS;   // 32 selection blocks
constexpr int kTopN = 16;
constexpr int kNInit = 2;
constexpr int kWIN  = 512;
constexpr float kNEG = -1e30f;
constexpr float kScale = 0.08838834764831845f; // 128^-0.5

constexpr int kPad    = 32;
constexpr int kKBRows = kT + kPad; // 2080
constexpr int kVTCols = kT + kPad; // 2080

// K2 (cmp-attn) LDS strides
constexpr int kQS2 = kD + 4;   // 132 floats
constexpr int kPS2 = 132;      // fp32 probs
constexpr int kPB2 = 136;      // bf16 probs

// K4 tiled attention (kQT=4: 4 waves, 4 queries, grid=512)
constexpr int kQT   = 4;
constexpr int kKstS = 136;        // staged K row stride (bf16 halfwords)
constexpr int kPSt  = 72;         // P row stride (fp16)

typedef __attribute__((ext_vector_type(8))) short short8;
typedef __attribute__((ext_vector_type(8))) _Float16 half8;
typedef __attribute__((ext_vector_type(2))) _Float16 half2v;
typedef __attribute__((ext_vector_type(4))) float floatx4;

// RNE float -> bf16 bits
__device__ inline short f2bf(float x) {
    unsigned u = __float_as_uint(x);
    unsigned r = (u + 0x7fffu + ((u >> 16) & 1u)) >> 16;
    return (short)r;
}

// ---------------------------------------------------------------------
// K1: fused staging.  blocks [0,2080): bf16 K rows + fp16 V^T cols,
// V^T stored with per-64-block key permutation col = 2l + (kt&1) + 32(kt>>1)
// (key = 16kt + l) so K4's P-writes pack as b32 pairs.
// blocks [2080,2208): mean-pool cmp_k fp32 + cmp V^T bf16.  block=(128)
// ---------------------------------------------------------------------
__global__ void k_stage(const float* __restrict__ k, const float* __restrict__ v,
                        short* __restrict__ kb, _Float16* __restrict__ vt,
                        float* __restrict__ cmp_k, short* __restrict__ cvt) {
    const int bid = blockIdx.x;
    const int d = threadIdx.x;
    if (bid < kKBRows) {
        const int row = bid;
        const int blk = row >> 6, w = row & 63;
        const int kt = w >> 4, l = w & 15;
        const int col = blk * kBS + l * 2 + (kt & 1) + (kt >> 1) * 32;
        if (row < kT) {
            kb[row * kD + d] = f2bf(k[(size_t)row * kD + d]);
            vt[(size_t)d * kVTCols + col] = (_Float16)v[(size_t)row * kD + d];
        } else {
            kb[row * kD + d] = 0;
            vt[(size_t)d * kVTCols + col] = (_Float16)0.f;
        }
    } else {
        const int m = bid - kKBRows;        // 0..127 (127 = zero pad row)
        float sk = 0.f, sv = 0.f;
        if (m < kM) {
            const int base = m * kST;
            #pragma unroll
            for (int i = 0; i < kKS; ++i) {
                sk += k[(size_t)(base + i) * kD + d];
                sv += v[(size_t)(base + i) * kD + d];
            }
            sk *= (1.0f / kKS);
            sv *= (1.0f / kKS);
        }
        cmp_k[m * kD + d] = sk;
        cvt[d * 128 + m] = f2bf(sv);
    }
}

// ---------------------------------------------------------------------
// K2: compressed attention + fused top-k, all 16 heads of one t.
// QK + softmax + slc_p + topk: fp32, arithmetic identical to R4..R10
// (selection-sensitive).  PV: bf16 MFMA.  grid=(T), block=(256)
// ---------------------------------------------------------------------
__global__ __launch_bounds__(256) void k_cmp_attn(
        const float* __restrict__ q, const float* __restrict__ cw,
        const float* __restrict__ cmp_k, const short* __restrict__ cvt,
        unsigned* __restrict__ sel_mask, float* __restrict__ out) {
    const int t = blockIdx.x;
    const int tid = threadIdx.x;
    const int wave = tid >> 6;
    const int lane = tid & 63;
    const int l15 = lane & 15;
    const int quad = lane >> 4;

    __shared__ float q_s[kHQ * kQS2];
    __shared__ float p_s[kHQ * kPS2];
    __shared__ short Pb[kHQ * kPB2];
    __shared__ float sp[kNB];

    for (int i = tid; i < kHQ * kD; i += 256) {
        int h = i >> 7, d = i & 127;
        q_s[h * kQS2 + d] = q[(size_t)t * kHQ * kD + i];
    }
    __syncthreads();

    const int nvalid = (t >= kKS - 1) ? min(kM, (t - (kKS - 1)) / kST + 1) : 0;

    for (int idx = tid; idx < nvalid * 4; idx += 256) {
        const int m = idx >> 2;
        const int h0 = (idx & 3) * 4;
        const float4* k4 = (const float4*)(cmp_k + (size_t)m * kD);
        float a0 = 0.f, a1 = 0.f, a2 = 0.f, a3 = 0.f;
        #pragma unroll
        for (int i = 0; i < kD / 4; ++i) {
            const float4 b = k4[i];
            const float4 qa = *(const float4*)&q_s[(h0 + 0) * kQS2 + i * 4];
            const float4 qb = *(const float4*)&q_s[(h0 + 1) * kQS2 + i * 4];
            const float4 qc = *(const float4*)&q_s[(h0 + 2) * kQS2 + i * 4];
            const float4 qd = *(const float4*)&q_s[(h0 + 3) * kQS2 + i * 4];
            a0 = fmaf(qa.x, b.x, fmaf(qa.y, b.y, fmaf(qa.z, b.z, fmaf(qa.w, b.w, a0))));
            a1 = fmaf(qb.x, b.x, fmaf(qb.y, b.y, fmaf(qb.z, b.z, fmaf(qb.w, b.w, a1))));
            a2 = fmaf(qc.x, b.x, fmaf(qc.y, b.y, fmaf(qc.z, b.z, fmaf(qc.w, b.w, a2))));
            a3 = fmaf(qd.x, b.x, fmaf(qd.y, b.y, fmaf(qd.z, b.z, fmaf(qd.w, b.w, a3))));
        }
        p_s[(h0 + 0) * kPS2 + m] = a0 * kScale;
        p_s[(h0 + 1) * kPS2 + m] = a1 * kScale;
        p_s[(h0 + 2) * kPS2 + m] = a2 * kScale;
        p_s[(h0 + 3) * kPS2 + m] = a3 * kScale;
    }
    __syncthreads();

    if (tid < kHQ) {
        float* p = p_s + tid * kPS2;
        short* pb = Pb + tid * kPB2;
        if (nvalid == 0) {
            for (int m = 0; m < 128; ++m) { p[m] = 0.f; pb[m] = 0; }
        } else {
            float mx = kNEG;
            for (int m = 0; m < nvalid; ++m) mx = fmaxf(mx, p[m]);
            float l = 0.f;
            for (int m = 0; m < nvalid; ++m) { float e = __expf(p[m] - mx); p[m] = e; l += e; }
            float inv = 1.f / l;
            for (int m = 0; m < nvalid; ++m) { float pn = p[m] * inv; p[m] = pn; pb[m] = f2bf(pn); }
            for (int m = nvalid; m < 128; ++m) { p[m] = 0.f; pb[m] = 0; }
        }
    }
    __syncthreads();

    if (tid < kNB) {
        const int b = tid;
        const int m0 = 4 * b;
        float acc = 0.f;
        for (int h = 0; h < kHQ; ++h) {
            const float* p = p_s + h * kPS2;
            float a = 0.f;
            a += p[m0];
            a += p[m0 + 1];
            a += p[m0 + 2];
            a += 0.5f * p[m0 + 3];
            if (m0 - 1 >= 0) a += 0.5f * p[m0 - 1];
            acc += a;
        }
        sp[b] = acc;
    }
    __syncthreads();

    // ---- fused top-k (identical semantics to the old k_topk) ----
    if (tid == 0) {
        const int cur = t / kBS;
        float vals[kNB];
        #pragma unroll
        for (int b = 0; b < kNB; ++b) {
            float x = sp[b];
            if (b > cur) x = kNEG;
            if (b < kNInit || b == cur) x = 1e30f;
            vals[b] = x;
        }
        unsigned mask = 0;
        for (int n = 0; n < kTopN; ++n) {
            float best = -3.0e38f; int bi = 0;
            #pragma unroll
            for (int b = 0; b < kNB; ++b) {
                bool taken = (mask >> b) & 1u;
                if (!taken && vals[b] > best) { best = vals[b]; bi = b; }
            }
            mask |= (1u << bi);
        }
        sel_mask[t] = mask;
    }

    const int dimbase = wave * 32;
    floatx4 o[2] = {{0,0,0,0},{0,0,0,0}};
    #pragma unroll
    for (int kc = 0; kc < 4; ++kc) {
        const short8 ap = *(const short8*)&Pb[l15 * kPB2 + kc * 32 + quad * 8];
        #pragma unroll
        for (int nt = 0; nt < 2; ++nt) {
            const short8 b = *(const short8*)(cvt + (size_t)(dimbase + nt * 16 + l15) * 128 + kc * 32 + quad * 8);
            o[nt] = __builtin_amdgcn_mfma_f32_16x16x32_bf16(ap, b, o[nt], 0, 0, 0);
        }
    }

    #pragma unroll
    for (int r = 0; r < 4; ++r) {
        const int head = quad * 4 + r;
        const float c0 = cw[((size_t)t * kHQ + head) * 3 + 0];
        const float w0 = 1.f / (1.f + __expf(-c0));
        #pragma unroll
        for (int nt = 0; nt < 2; ++nt)
            out[((size_t)t * kHQ + head) * kD + dimbase + nt * 16 + l15] = w0 * o[nt][r];
    }
}

// ---------------------------------------------------------------------
// K4: query-tiled select+SWA attention (kQT=4, double-buffered Kst).
// One workgroup = 4 consecutive t's x 16 heads, 4 waves.  grid=(T/4).
// Per union block: QK from staged Kst (bf16), two masked online
// softmaxes sharing scores (shared-exp trick), PV f16 MFMA with
// prefetched V frags.  P written as packed b32 via the vt permutation.
// ---------------------------------------------------------------------
__global__ __launch_bounds__(256, 2) void k_attn_tile(
        const float* __restrict__ q, const short* __restrict__ kb,
        const _Float16* __restrict__ vt, const float* __restrict__ cw,
        const unsigned* __restrict__ sel_mask, float* __restrict__ out) {
    const int t0 = blockIdx.x * kQT;
    const int tid = threadIdx.x;
    const int wave = tid >> 6;
    const int lane = tid & 63;
    const int l15 = lane & 15;
    const int quad = lane >> 4;

    __shared__ short Kst[2][64 * kKstS];         // 2 x 17.4 KB staged K
    __shared__ _Float16 Psel[64 * kPSt];         // 9.2 KB
    __shared__ _Float16 Pswa[64 * kPSt];         // 9.2 KB
    __shared__ float alphaS[64], alphaW[64], linvS[64], linvW[64];
    __shared__ int blks[33];
    __shared__ int nblk_s;
    __shared__ unsigned selm_s[kQT];

    const int t_w = t0 + wave;

    // A-fragments: q[t_w][head=l15][.] * kScale -> bf16
    short8 aq[4];
    {
        const float* qp = q + ((size_t)t_w * kHQ + l15) * kD + quad * 8;
        #pragma unroll
        for (int c = 0; c < 4; ++c) {
            const float4 f0 = *(const float4*)(qp + c * 32);
            const float4 f1 = *(const float4*)(qp + c * 32 + 4);
            short8 a;
            a[0] = f2bf(f0.x * kScale); a[1] = f2bf(f0.y * kScale);
            a[2] = f2bf(f0.z * kScale); a[3] = f2bf(f0.w * kScale);
            a[4] = f2bf(f1.x * kScale); a[5] = f2bf(f1.y * kScale);
            a[6] = f2bf(f1.z * kScale); a[7] = f2bf(f1.w * kScale);
            aq[c] = a;
        }
    }

    if (tid < kQT) selm_s[tid] = sel_mask[t0 + tid];
    __syncthreads();

    const unsigned selm_w = selm_s[wave];
    const unsigned u_union = selm_s[0] | selm_s[1] | selm_s[2] | selm_s[3];
    const int cur_max = (t0 + kQT - 1) >> 6;
    if (tid == 0) {
        int n = 0;
        for (int b = 0; b <= cur_max; ++b) {
            const bool bs = (u_union >> b) & 1u;
            const bool bw = (b * kBS + kBS - 1) >= (t0 - (kWIN - 1));
            if (bs || bw) blks[n++] = b;
        }
        nblk_s = n;
    }
    __syncthreads();
    const int nblk = nblk_s;

    // prestage blks[0] into Kst[0]
    {
        const int b0 = blks[0];
        const int row = tid >> 2, seg = tid & 3;
        const short* src = kb + (size_t)(b0 * kBS + row) * kD + seg * 32;
        short* dst = &Kst[0][row * kKstS + seg * 32];
        #pragma unroll
        for (int i = 0; i < 4; ++i)
            *(short8*)(dst + i * 8) = *(const short8*)(src + i * 8);
    }

    float msel[4], lsel[4], mswa[4], lswa[4];
    #pragma unroll
    for (int r = 0; r < 4; ++r) { msel[r] = kNEG; lsel[r] = 0.f; mswa[r] = kNEG; lswa[r] = 0.f; }
    floatx4 osel[kQT][2], oswa[kQT][2];
    #pragma unroll
    for (int mt = 0; mt < kQT; ++mt)
        #pragma unroll
        for (int nt = 0; nt < 2; ++nt) {
            osel[mt][nt] = (floatx4){0,0,0,0};
            oswa[mt][nt] = (floatx4){0,0,0,0};
        }
    const int dimw = wave * 32;

    __syncthreads();   // prestage visible

    for (int i = 0; i < nblk; ++i) {
        const int b = blks[i];
        const int cur = i & 1;
        const bool bsel = (u_union >> b) & 1u;
        const bool bswa = (b * kBS + kBS - 1) >= (t0 - (kWIN - 1));

        // ---- early global loads: V frags (this block) + next K rows ----
        half8 vf[2][2];
        #pragma unroll
        for (int nt = 0; nt < 2; ++nt)
            #pragma unroll
            for (int kc = 0; kc < 2; ++kc)
                vf[nt][kc] = *(const half8*)(vt + (size_t)(dimw + nt * 16 + l15) * kVTCols
                                             + b * kBS + kc * 32 + quad * 8);
        short8 kreg[4];
        {
            const int nb_ = (i + 1 < nblk) ? blks[i + 1] : b;
            const int row = tid >> 2, seg = tid & 3;
            const short* src = kb + (size_t)(nb_ * kBS + row) * kD + seg * 32;
            #pragma unroll
            for (int j = 0; j < 4; ++j)
                kreg[j] = *(const short8*)(src + j * 8);
        }

        // ---- QK from Kst[cur]: 16 heads x 64 keys (scores pre-scaled) ----
        floatx4 acc[4];
        #pragma unroll
        for (int kt = 0; kt < 4; ++kt) {
            acc[kt] = (floatx4){0,0,0,0};
            #pragma unroll
            for (int c = 0; c < 4; ++c) {
                const short8 bf = *(const short8*)&Kst[cur][(kt * 16 + l15) * kKstS + c * 32 + quad * 8];
                acc[kt] = __builtin_amdgcn_mfma_f32_16x16x32_bf16(aq[c], bf, acc[kt], 0, 0, 0);
            }
        }

        const bool mem = (selm_w >> b) & 1u;
        bool ca[4], wi[4];
        #pragma unroll
        for (int kt = 0; kt < 4; ++kt) {
            const int key = b * kBS + kt * 16 + l15;
            ca[kt] = key <= t_w;
            wi[kt] = ca[kt] && (t_w - key) < kWIN;
        }

        // ---- online softmax (shared-exp between sel and swa) ----
        float axs[4], axw[4];
        #pragma unroll
        for (int r = 0; r < 4; ++r) {
            float mxs = kNEG, mxw = kNEG;
            #pragma unroll
            for (int kt = 0; kt < 4; ++kt) {
                const float s = acc[kt][r];
                if (mem && ca[kt]) mxs = fmaxf(mxs, s);
                if (wi[kt]) mxw = fmaxf(mxw, s);
            }
            #pragma unroll
            for (int off = 8; off; off >>= 1) {
                mxs = fmaxf(mxs, __shfl_xor(mxs, off, 16));
                mxw = fmaxf(mxw, __shfl_xor(mxw, off, 16));
            }
            const float msn = fmaxf(msel[r], mxs);
            const float mwn = fmaxf(mswa[r], mxw);
            axs[r] = __expf(msel[r] - msn);
            axw[r] = __expf(mswa[r] - mwn);

            float es[4], ew[4];
            if (mem) {
                const float cr = __expf(msn - mwn);
                #pragma unroll
                for (int kt = 0; kt < 4; ++kt) {
                    const float e0 = ca[kt] ? __expf(acc[kt][r] - msn) : 0.f;
                    es[kt] = e0;
                    ew[kt] = wi[kt] ? e0 * cr : 0.f;
                }
            } else {
                #pragma unroll
                for (int kt = 0; kt < 4; ++kt) {
                    es[kt] = 0.f;
                    ew[kt] = wi[kt] ? __expf(acc[kt][r] - mwn) : 0.f;
                }
            }
            float sums = (es[0] + es[1]) + (es[2] + es[3]);
            float sumw = (ew[0] + ew[1]) + (ew[2] + ew[3]);
            #pragma unroll
            for (int off = 8; off; off >>= 1) {
                sums += __shfl_xor(sums, off, 16);
                sumw += __shfl_xor(sumw, off, 16);
            }
            lsel[r] = lsel[r] * axs[r] + sums; msel[r] = msn;
            lswa[r] = lswa[r] * axw[r] + sumw; mswa[r] = mwn;

            // packed P writes: perm col = 2*l15 + (kt&1) + 32*(kt>>1)
            const int prow = (wave * 16 + quad * 4 + r) * kPSt;
            if (bsel) {
                *(half2v*)&Psel[prow + 2 * l15]      = (half2v){(_Float16)es[0], (_Float16)es[1]};
                *(half2v*)&Psel[prow + 32 + 2 * l15] = (half2v){(_Float16)es[2], (_Float16)es[3]};
            }
            if (bswa) {
                *(half2v*)&Pswa[prow + 2 * l15]      = (half2v){(_Float16)ew[0], (_Float16)ew[1]};
                *(half2v*)&Pswa[prow + 32 + 2 * l15] = (half2v){(_Float16)ew[2], (_Float16)ew[3]};
            }
        }
        if (l15 == 0) {
            *(float4*)&alphaS[wave * 16 + quad * 4] = make_float4(axs[0], axs[1], axs[2], axs[3]);
            *(float4*)&alphaW[wave * 16 + quad * 4] = make_float4(axw[0], axw[1], axw[2], axw[3]);
        }
        __syncthreads();   // P + alpha ready

        // ---- PV: wave owns dims [32w,32w+32); vf prefetched ----
        if (bsel) {
            #pragma unroll
            for (int mt = 0; mt < kQT; ++mt) {
                const float4 a4 = *(const float4*)&alphaS[mt * 16 + quad * 4];
                const float av[4] = {a4.x, a4.y, a4.z, a4.w};
                #pragma unroll
                for (int nt = 0; nt < 2; ++nt)
                    #pragma unroll
                    for (int r = 0; r < 4; ++r) osel[mt][nt][r] *= av[r];
                #pragma unroll
                for (int kc = 0; kc < 2; ++kc) {
                    const half8 ap = *(const half8*)&Psel[(mt * 16 + l15) * kPSt + kc * 32 + quad * 8];
                    #pragma unroll
                    for (int nt = 0; nt < 2; ++nt)
                        osel[mt][nt] = __builtin_amdgcn_mfma_f32_16x16x32_f16(ap, vf[nt][kc], osel[mt][nt], 0, 0, 0);
                }
            }
        }
        if (bswa) {
            #pragma unroll
            for (int mt = 0; mt < kQT; ++mt) {
                const float4 a4 = *(const float4*)&alphaW[mt * 16 + quad * 4];
                const float av[4] = {a4.x, a4.y, a4.z, a4.w};
                #pragma unroll
                for (int nt = 0; nt < 2; ++nt)
                    #pragma unroll
                    for (int r = 0; r < 4; ++r) oswa[mt][nt][r] *= av[r];
                #pragma unroll
                for (int kc = 0; kc < 2; ++kc) {
                    const half8 ap = *(const half8*)&Pswa[(mt * 16 + l15) * kPSt + kc * 32 + quad * 8];
                    #pragma unroll
                    for (int nt = 0; nt < 2; ++nt)
                        oswa[mt][nt] = __builtin_amdgcn_mfma_f32_16x16x32_f16(ap, vf[nt][kc], oswa[mt][nt], 0, 0, 0);
                }
            }
        }

        // ---- stage next block into the other Kst buffer ----
        if (i + 1 < nblk) {
            const int row = tid >> 2, seg = tid & 3;
            short* dst = &Kst[1 - cur][row * kKstS + seg * 32];
            #pragma unroll
            for (int j = 0; j < 4; ++j)
                *(short8*)(dst + j * 8) = kreg[j];
        }
        __syncthreads();   // next Kst visible; P reads done
    }

    // ---- epilogue: normalizers + sigmoid combine ----
    if (l15 == 0) {
        *(float4*)&linvS[wave * 16 + quad * 4] =
            make_float4(1.f / lsel[0], 1.f / lsel[1], 1.f / lsel[2], 1.f / lsel[3]);
        *(float4*)&linvW[wave * 16 + quad * 4] =
            make_float4(1.f / lswa[0], 1.f / lswa[1], 1.f / lswa[2], 1.f / lswa[3]);
    }
    __syncthreads();

    #pragma unroll
    for (int mt = 0; mt < kQT; ++mt) {
        const int tt = t0 + mt;
        #pragma unroll
        for (int r = 0; r < 4; ++r) {
            const int h = quad * 4 + r;
            const float ls = linvS[mt * 16 + h];
            const float lw = linvW[mt * 16 + h];
            const float c1 = cw[((size_t)tt * kHQ + h) * 3 + 1];
            const float c2 = cw[((size_t)tt * kHQ + h) * 3 + 2];
            const float w1 = 1.f / (1.f + __expf(-c1));
            const float w2 = 1.f / (1.f + __expf(-c2));
            #pragma unroll
            for (int nt = 0; nt < 2; ++nt) {
                const int dim = dimw + nt * 16 + l15;
                float* op = out + ((size_t)tt * kHQ + h) * kD + dim;
                *op += w1 * osel[mt][nt][r] * ls + w2 * oswa[mt][nt][r] * lw;
            }
        }
    }
}

// ---------------------------------------------------------------------
extern "C" void kernel_launch(void* const* d_in, const int* in_sizes, int n_in,
                              void* d_out, int out_size, void* d_ws, size_t ws_size,
                              hipStream_t stream) {
    const float* q  = (const float*)d_in[0];
    const float* k  = (const float*)d_in[1];
    const float* v  = (const float*)d_in[2];
    const float* cw = (const float*)d_in[3];
    float* out = (float*)d_out;

    float* ws = (float*)d_ws;
    float* cmp_k = ws;                                   // 128*128 fp32
    unsigned* sel_mask = (unsigned*)(cmp_k + 128 * kD);  // T u32
    short* kb      = (short*)(sel_mask + kT);            // kKBRows*kD bf16
    _Float16* vt   = (_Float16*)(kb + (size_t)kKBRows * kD);  // kD*kVTCols fp16
    short* cvt     = (short*)(vt + (size_t)kD * kVTCols);     // 128*128 bf16

    k_stage<<<dim3(kKBRows + 128), dim3(kD), 0, stream>>>(k, v, kb, vt, cmp_k, cvt);
    k_cmp_attn<<<dim3(kT), dim3(256), 0, stream>>>(q, cw, cmp_k, cvt, sel_mask, out);
    k_attn_tile<<<dim3(kT / kQT), dim3(256), 0, stream>>>(q, kb, vt, cw, sel_mask, out);
}